// Round 1
// baseline (9.292 us; speedup 1.0000x reference)
//
#include <hip/hip_runtime.h>

// Attention_79998060855419:
// The reference network ends with entmax_bisect over a SINGLETON last
// dimension (x has shape [N, 1]). For d==1:
//   tau_hi == tau_lo  (since (1/1)^(alpha-1) == 1)  -> dm == 0 forever
//   p_m = clip(x - tau_lo, 0)^(1/(alpha-1)) with x - tau_lo ~= 1 (finite, > 0)
//   return p_m / sum(p_m, axis=-1) == p_m / p_m == 1.0 exactly (IEEE x/x).
// Hence the output is identically 1.0f for every row, independent of all
// inputs. The kernel is a constant fill of out_size f32 values.

__global__ void fill_ones_kernel(float* __restrict__ out, int n) {
    int idx = blockIdx.x * blockDim.x + threadIdx.x;
    int i4 = idx * 4;
    if (i4 + 3 < n) {
        *reinterpret_cast<float4*>(out + i4) = make_float4(1.0f, 1.0f, 1.0f, 1.0f);
    } else if (i4 < n) {
        for (int j = i4; j < n; ++j) out[j] = 1.0f;
    }
}

extern "C" void kernel_launch(void* const* d_in, const int* in_sizes, int n_in,
                              void* d_out, int out_size, void* d_ws, size_t ws_size,
                              hipStream_t stream) {
    (void)d_in; (void)in_sizes; (void)n_in; (void)d_ws; (void)ws_size;
    float* out = reinterpret_cast<float*>(d_out);
    const int n = out_size;               // 131072 (N x 1)
    const int block = 256;
    const int n_vec = (n + 3) / 4;        // one thread per float4
    const int grid = (n_vec + block - 1) / block;
    fill_ones_kernel<<<grid, block, 0, stream>>>(out, n);
}